// Round 13
// baseline (85.250 us; speedup 1.0000x reference)
//
#include <hip/hip_runtime.h>
#include <math.h>

// HeteAttention capsule routing, MI355X — R8 verified compute structure
// (bf16-packed register-resident z, DPP softmax, permlane k-reduce) with
// TWO batch elements interleaved per block: halves barriers-per-b (8->4)
// and doubles combine parallelism (256 threads instead of 128).
// No prefetch, no custom barriers, no outer loop (R4-R12 lessons: every
// latency-hiding variant lost to vmcnt-drain / spill / occupancy).
// B=4096, n=1, N=128, F=8 facets, D=16, n_iter=4, C=F*D=128.
// Grid 2048 blocks x 512 thr (8 waves); block handles b1=2*bid, b2=b1+1.
// Lane map (per wave): cg = lane&15 owns channels c = cg*8..+7; lane bit0 =
// facet half (facet = cg>>1); kgl = lane>>4; kq = wave*4+kgl owns k=kq*4..+3
// — for BOTH b1 (zp1) and b2 (zp2), 16+16 packed VGPRs.
// Staging (32 VGPR) lives only in the prologue (load+pack b1, then reuse
// for b2) so the main loop's live set fits (512,6)'s 85-VGPR cap.
// Combine: t<128 handles b1 channel t; t in [128,256) handles b2 channel
// t-128 (facet = 16-lane DPP row in every wave). Softmax max-pass dropped
// (|logit|<=1); exp2 with log2e folded into broadcast u.
// absmax ~0.0156 (bf16 z) vs threshold 0.0597.

#define CC 128
#define ZSZ (128 * CC)
#define LOG2E 1.44269504088896340736f

typedef float f32x2 __attribute__((ext_vector_type(2)));
typedef unsigned u32x2 __attribute__((ext_vector_type(2)));

template<int CTRL>
__device__ __forceinline__ float dpp_add(float x) {
    int y = __builtin_amdgcn_update_dpp(0, __float_as_int(x), CTRL, 0xF, 0xF, true);
    return x + __int_as_float(y);
}
#define DPP_XOR1 0xB1   // quad_perm [1,0,3,2]
#define DPP_XOR2 0x4E   // quad_perm [2,3,0,1]
#define DPP_HMIR 0x141  // row_half_mirror (^7; ==^4 when bits 0,1 uniform)
#define DPP_MIR  0x140  // row_mirror      (^15; ==^8 when bits 0..2 uniform)

__device__ __forceinline__ f32x2 xor16_add2(f32x2 v) {
    u32x2 r0 = __builtin_amdgcn_permlane16_swap(__float_as_uint(v.x), __float_as_uint(v.x), false, false);
    u32x2 r1 = __builtin_amdgcn_permlane16_swap(__float_as_uint(v.y), __float_as_uint(v.y), false, false);
    f32x2 o;
    o.x = __uint_as_float(r0.x) + __uint_as_float(r0.y);
    o.y = __uint_as_float(r1.x) + __uint_as_float(r1.y);
    return o;
}
__device__ __forceinline__ f32x2 xor32_add2(f32x2 v) {
    u32x2 r0 = __builtin_amdgcn_permlane32_swap(__float_as_uint(v.x), __float_as_uint(v.x), false, false);
    u32x2 r1 = __builtin_amdgcn_permlane32_swap(__float_as_uint(v.y), __float_as_uint(v.y), false, false);
    f32x2 o;
    o.x = __uint_as_float(r0.x) + __uint_as_float(r0.y);
    o.y = __uint_as_float(r1.x) + __uint_as_float(r1.y);
    return o;
}
__device__ __forceinline__ float rsq_guard(float s) {
    return __builtin_amdgcn_rsqf(fmaxf(s, 1e-24f));
}
__device__ __forceinline__ unsigned pack_bf16(float lo, float hi) {
    unsigned r;
    asm("v_cvt_pk_bf16_f32 %0, %1, %2" : "=v"(r) : "v"(lo), "v"(hi));
    return r;
}
__device__ __forceinline__ f32x2 unpack_bf16(unsigned u) {
    f32x2 r;
    r.x = __uint_as_float(u << 16);
    r.y = __uint_as_float(u & 0xFFFF0000u);
    return r;
}

__global__ __launch_bounds__(512, 6)
void hete_routing_kernel(const float* __restrict__ feat,   // [B, 128]
                         const float* __restrict__ mp,     // [B, 128, 128]
                         float* __restrict__ out)          // [B, 128]
{
    __shared__ float part1[8][CC];   // 4 KB: b1 per-wave k-partials
    __shared__ float part2[8][CC];   // 4 KB: b2 per-wave k-partials
    __shared__ float u1_s[CC];       // b1 broadcast u (pre-scaled log2e)
    __shared__ float u2_s[CC];       // b2 broadcast u

    const int t = threadIdx.x;
    const int wave = t >> 6;          // 0..7
    const int lane = t & 63;
    const int cg = lane & 15;
    const int kgl = lane >> 4;        // 0..3
    const int kq = wave * 4 + kgl;    // 0..31, owns k = kq*4 .. kq*4+3
    const int c0 = cg * 8;
    const int b1 = blockIdx.x * 2;
    const int b2 = b1 + 1;

    // ---- prologue: load + normalize + pack b1, then b2 (staging reused) ----
    unsigned zp1[4][4], zp2[4][4];
    {
        float4 A[4], Bv[4];
        const float* z1 = mp + (size_t)b1 * ZSZ + kq * 4 * CC + c0;
#pragma unroll
        for (int kk = 0; kk < 4; ++kk) {
            A[kk]  = *reinterpret_cast<const float4*>(z1 + kk * CC);
            Bv[kk] = *reinterpret_cast<const float4*>(z1 + kk * CC + 4);
        }
#pragma unroll
        for (int kk = 0; kk < 4; ++kk) {
            float s = A[kk].x * A[kk].x + A[kk].y * A[kk].y
                    + A[kk].z * A[kk].z + A[kk].w * A[kk].w
                    + Bv[kk].x * Bv[kk].x + Bv[kk].y * Bv[kk].y
                    + Bv[kk].z * Bv[kk].z + Bv[kk].w * Bv[kk].w;
            s = dpp_add<DPP_XOR1>(s);
            const float inv = rsq_guard(s);
            zp1[kk][0] = pack_bf16(A[kk].x * inv,  A[kk].y * inv);
            zp1[kk][1] = pack_bf16(A[kk].z * inv,  A[kk].w * inv);
            zp1[kk][2] = pack_bf16(Bv[kk].x * inv, Bv[kk].y * inv);
            zp1[kk][3] = pack_bf16(Bv[kk].z * inv, Bv[kk].w * inv);
        }
        const float* z2 = mp + (size_t)b2 * ZSZ + kq * 4 * CC + c0;
#pragma unroll
        for (int kk = 0; kk < 4; ++kk) {
            A[kk]  = *reinterpret_cast<const float4*>(z2 + kk * CC);
            Bv[kk] = *reinterpret_cast<const float4*>(z2 + kk * CC + 4);
        }
#pragma unroll
        for (int kk = 0; kk < 4; ++kk) {
            float s = A[kk].x * A[kk].x + A[kk].y * A[kk].y
                    + A[kk].z * A[kk].z + A[kk].w * A[kk].w
                    + Bv[kk].x * Bv[kk].x + Bv[kk].y * Bv[kk].y
                    + Bv[kk].z * Bv[kk].z + Bv[kk].w * Bv[kk].w;
            s = dpp_add<DPP_XOR1>(s);
            const float inv = rsq_guard(s);
            zp2[kk][0] = pack_bf16(A[kk].x * inv,  A[kk].y * inv);
            zp2[kk][1] = pack_bf16(A[kk].z * inv,  A[kk].w * inv);
            zp2[kk][2] = pack_bf16(Bv[kk].x * inv, Bv[kk].y * inv);
            zp2[kk][3] = pack_bf16(Bv[kk].z * inv, Bv[kk].w * inv);
        }
    }

    // ---- x_hat: t<128 -> b1 channel t; t in [128,256) -> b2 channel t-128 ----
    float xh = 0.f;
    if (t < 256) {
        const int ch = t & 127;
        const int bb = (t < CC) ? b1 : b2;
        const float xv = feat[(size_t)bb * CC + ch];
        float s = xv * xv;
        s = dpp_add<DPP_XOR1>(s);
        s = dpp_add<DPP_XOR2>(s);
        s = dpp_add<DPP_HMIR>(s);
        s = dpp_add<DPP_MIR>(s);
        xh = xv * rsq_guard(s);
        if (t < CC) u1_s[ch] = xh * LOG2E;
        else        u2_s[ch] = xh * LOG2E;
    }
    __syncthreads();

    // ---- routing iterations (both b's per barrier interval) ----
#pragma unroll
    for (int it = 0; it < 4; ++it) {
        // -------- b1 pass --------
        {
            f32x2 ur[4];
            const float4 Ua = *reinterpret_cast<const float4*>(&u1_s[c0]);
            const float4 Ub = *reinterpret_cast<const float4*>(&u1_s[c0 + 4]);
            ur[0] = f32x2{Ua.x, Ua.y};  ur[1] = f32x2{Ua.z, Ua.w};
            ur[2] = f32x2{Ub.x, Ub.y};  ur[3] = f32x2{Ub.z, Ub.w};
            f32x2 pu[4] = {f32x2{0.f,0.f}, f32x2{0.f,0.f}, f32x2{0.f,0.f}, f32x2{0.f,0.f}};
#pragma unroll
            for (int kk = 0; kk < 4; ++kk) {
                const f32x2 z0 = unpack_bf16(zp1[kk][0]);
                const f32x2 z1 = unpack_bf16(zp1[kk][1]);
                const f32x2 z2 = unpack_bf16(zp1[kk][2]);
                const f32x2 z3 = unpack_bf16(zp1[kk][3]);
                f32x2 acc = z0 * ur[0];
                acc += z1 * ur[1];
                acc += z2 * ur[2];
                acc += z3 * ur[3];
                const float l = dpp_add<DPP_XOR1>(acc.x + acc.y);
                const float e = __builtin_amdgcn_exp2f(l);
                float su = dpp_add<DPP_XOR2>(e);
                su = dpp_add<DPP_HMIR>(su);
                su = dpp_add<DPP_MIR>(su);
                const float wk = e * __builtin_amdgcn_rcpf(su);
                const f32x2 ws = {wk, wk};
                pu[0] += z0 * ws;
                pu[1] += z1 * ws;
                pu[2] += z2 * ws;
                pu[3] += z3 * ws;
            }
#pragma unroll
            for (int j = 0; j < 4; ++j) {
                pu[j] = xor16_add2(pu[j]);
                pu[j] = xor32_add2(pu[j]);
            }
            if (kgl == 0) {
                float* dst = &part1[wave][c0];
                *reinterpret_cast<float4*>(dst)     = make_float4(pu[0].x, pu[0].y, pu[1].x, pu[1].y);
                *reinterpret_cast<float4*>(dst + 4) = make_float4(pu[2].x, pu[2].y, pu[3].x, pu[3].y);
            }
        }
        // -------- b2 pass --------
        {
            f32x2 ur[4];
            const float4 Ua = *reinterpret_cast<const float4*>(&u2_s[c0]);
            const float4 Ub = *reinterpret_cast<const float4*>(&u2_s[c0 + 4]);
            ur[0] = f32x2{Ua.x, Ua.y};  ur[1] = f32x2{Ua.z, Ua.w};
            ur[2] = f32x2{Ub.x, Ub.y};  ur[3] = f32x2{Ub.z, Ub.w};
            f32x2 pu[4] = {f32x2{0.f,0.f}, f32x2{0.f,0.f}, f32x2{0.f,0.f}, f32x2{0.f,0.f}};
#pragma unroll
            for (int kk = 0; kk < 4; ++kk) {
                const f32x2 z0 = unpack_bf16(zp2[kk][0]);
                const f32x2 z1 = unpack_bf16(zp2[kk][1]);
                const f32x2 z2 = unpack_bf16(zp2[kk][2]);
                const f32x2 z3 = unpack_bf16(zp2[kk][3]);
                f32x2 acc = z0 * ur[0];
                acc += z1 * ur[1];
                acc += z2 * ur[2];
                acc += z3 * ur[3];
                const float l = dpp_add<DPP_XOR1>(acc.x + acc.y);
                const float e = __builtin_amdgcn_exp2f(l);
                float su = dpp_add<DPP_XOR2>(e);
                su = dpp_add<DPP_HMIR>(su);
                su = dpp_add<DPP_MIR>(su);
                const float wk = e * __builtin_amdgcn_rcpf(su);
                const f32x2 ws = {wk, wk};
                pu[0] += z0 * ws;
                pu[1] += z1 * ws;
                pu[2] += z2 * ws;
                pu[3] += z3 * ws;
            }
#pragma unroll
            for (int j = 0; j < 4; ++j) {
                pu[j] = xor16_add2(pu[j]);
                pu[j] = xor32_add2(pu[j]);
            }
            if (kgl == 0) {
                float* dst = &part2[wave][c0];
                *reinterpret_cast<float4*>(dst)     = make_float4(pu[0].x, pu[0].y, pu[1].x, pu[1].y);
                *reinterpret_cast<float4*>(dst + 4) = make_float4(pu[2].x, pu[2].y, pu[3].x, pu[3].y);
            }
        }
        __syncthreads();

        // -------- combine: 256 threads, b1 by t<128, b2 by t in [128,256) --------
        if (t < 256) {
            const int ch = t & 127;
            const float (*pp)[CC] = (t < CC) ? part1 : part2;
            float un = xh;
#pragma unroll
            for (int j = 0; j < 8; ++j) un += pp[j][ch];
            if (it < 3) {
                float s = un * un;
                s = dpp_add<DPP_XOR1>(s);
                s = dpp_add<DPP_XOR2>(s);
                s = dpp_add<DPP_HMIR>(s);
                s = dpp_add<DPP_MIR>(s);
                const float uo = un * rsq_guard(s) * LOG2E;
                if (t < CC) u1_s[ch] = uo;
                else        u2_s[ch] = uo;
            } else {
                const int bb = (t < CC) ? b1 : b2;
                out[(size_t)bb * CC + ch] = un;
            }
        }
        if (it < 3) __syncthreads();
    }
}

extern "C" void kernel_launch(void* const* d_in, const int* in_sizes, int n_in,
                              void* d_out, int out_size, void* d_ws, size_t ws_size,
                              hipStream_t stream) {
    const float* feat = (const float*)d_in[0];   // features [B,1,128] fp32
    const float* mp   = (const float*)d_in[1];   // metapath [B,1,128,128] fp32
    float* out = (float*)d_out;                  // [B,128] fp32
    const int B = in_sizes[0] / CC;              // 4096
    hete_routing_kernel<<<B / 2, 512, 0, stream>>>(feat, mp, out);
}

// Round 14
// 61.690 us; speedup vs baseline: 1.3819x; 1.3819x over previous
//
#include <hip/hip_runtime.h>
#include <math.h>

// HeteAttention capsule routing, MI355X — R8 compute core (bf16-packed
// register-resident z, DPP softmax, permlane k-reduce) with the serial
// combine ELIMINATED: every lane reads 2 of the 8 wave-partial rows and
// completes the cross-wave sum with permlane16/32 swaps, so u lives in
// registers in ALL waves and each iteration needs exactly ONE barrier
// (4 per b instead of 8, no 2-of-8-wave serial phase).
// B=4096, n=1, N=128, F=8 facets, D=16, n_iter=4, C=F*D=128.
// Grid 4096 blocks x 512 thr (8 waves); one b per block; (512,6).
// Lane map (per wave): cg = lane&15 owns channels c = cg*8..+7; lane bit0 =
// facet half (facet = cg>>1); kgl = lane>>4; kq = wave*4+kgl owns k=kq*4..+3.
// part[2][8][132]: double-buffered per-wave k-partials (stride 132 floats
// keeps float4 alignment; ~2x bank aliasing on combine reads is cheap).
// Race-freedom with 1 barrier/iter: iter it writes part[it&1] pre-barrier,
// reads it post-barrier; a wave can only re-write buffer p at it+2, which is
// after barrier(it+1), which all waves reach only after their it-reads.
// x per-lane in registers (xh[4]); norms via local sumsq + DPP XOR1.
// Softmax max-pass dropped (|logit|<=1); exp2 with log2e folded into ur.
// absmax ~0.0156 (bf16 z) vs threshold 0.0597.

#define CC 128
#define ZSZ (128 * CC)
#define PST 132
#define LOG2E 1.44269504088896340736f

typedef float f32x2 __attribute__((ext_vector_type(2)));
typedef unsigned u32x2 __attribute__((ext_vector_type(2)));

template<int CTRL>
__device__ __forceinline__ float dpp_add(float x) {
    int y = __builtin_amdgcn_update_dpp(0, __float_as_int(x), CTRL, 0xF, 0xF, true);
    return x + __int_as_float(y);
}
#define DPP_XOR1 0xB1   // quad_perm [1,0,3,2]
#define DPP_XOR2 0x4E   // quad_perm [2,3,0,1]
#define DPP_HMIR 0x141  // row_half_mirror (^7; ==^4 when bits 0,1 uniform)
#define DPP_MIR  0x140  // row_mirror      (^15; ==^8 when bits 0..2 uniform)

__device__ __forceinline__ f32x2 xor16_add2(f32x2 v) {
    u32x2 r0 = __builtin_amdgcn_permlane16_swap(__float_as_uint(v.x), __float_as_uint(v.x), false, false);
    u32x2 r1 = __builtin_amdgcn_permlane16_swap(__float_as_uint(v.y), __float_as_uint(v.y), false, false);
    f32x2 o;
    o.x = __uint_as_float(r0.x) + __uint_as_float(r0.y);
    o.y = __uint_as_float(r1.x) + __uint_as_float(r1.y);
    return o;
}
__device__ __forceinline__ f32x2 xor32_add2(f32x2 v) {
    u32x2 r0 = __builtin_amdgcn_permlane32_swap(__float_as_uint(v.x), __float_as_uint(v.x), false, false);
    u32x2 r1 = __builtin_amdgcn_permlane32_swap(__float_as_uint(v.y), __float_as_uint(v.y), false, false);
    f32x2 o;
    o.x = __uint_as_float(r0.x) + __uint_as_float(r0.y);
    o.y = __uint_as_float(r1.x) + __uint_as_float(r1.y);
    return o;
}
__device__ __forceinline__ float rsq_guard(float s) {
    return __builtin_amdgcn_rsqf(fmaxf(s, 1e-24f));
}
__device__ __forceinline__ unsigned pack_bf16(float lo, float hi) {
    unsigned r;
    asm("v_cvt_pk_bf16_f32 %0, %1, %2" : "=v"(r) : "v"(lo), "v"(hi));
    return r;
}
__device__ __forceinline__ f32x2 unpack_bf16(unsigned u) {
    f32x2 r;
    r.x = __uint_as_float(u << 16);
    r.y = __uint_as_float(u & 0xFFFF0000u);
    return r;
}

__global__ __launch_bounds__(512, 6)
void hete_routing_kernel(const float* __restrict__ feat,   // [B, 128]
                         const float* __restrict__ mp,     // [B, 128, 128]
                         float* __restrict__ out)          // [B, 128]
{
    __shared__ float part[2][8][PST];   // 8.4 KB: dbuf x wave x channel

    const int t = threadIdx.x;
    const int wave = t >> 6;          // 0..7
    const int lane = t & 63;
    const int cg = lane & 15;
    const int kgl = lane >> 4;        // 0..3
    const int kq = wave * 4 + kgl;    // 0..31, owns k = kq*4 .. kq*4+3
    const int c0 = cg * 8;
    const int b = blockIdx.x;

    // ---- prologue: load z slice fp32, normalize per (k,facet), pack bf16 ----
    unsigned zp[4][4];
    {
        const float* zb = mp + (size_t)b * ZSZ + kq * 4 * CC + c0;
        float4 A[4], Bv[4];
#pragma unroll
        for (int kk = 0; kk < 4; ++kk) {
            A[kk]  = *reinterpret_cast<const float4*>(zb + kk * CC);
            Bv[kk] = *reinterpret_cast<const float4*>(zb + kk * CC + 4);
        }
#pragma unroll
        for (int kk = 0; kk < 4; ++kk) {
            float s = A[kk].x * A[kk].x + A[kk].y * A[kk].y
                    + A[kk].z * A[kk].z + A[kk].w * A[kk].w
                    + Bv[kk].x * Bv[kk].x + Bv[kk].y * Bv[kk].y
                    + Bv[kk].z * Bv[kk].z + Bv[kk].w * Bv[kk].w;
            s = dpp_add<DPP_XOR1>(s);
            const float inv = rsq_guard(s);
            zp[kk][0] = pack_bf16(A[kk].x * inv,  A[kk].y * inv);
            zp[kk][1] = pack_bf16(A[kk].z * inv,  A[kk].w * inv);
            zp[kk][2] = pack_bf16(Bv[kk].x * inv, Bv[kk].y * inv);
            zp[kk][3] = pack_bf16(Bv[kk].z * inv, Bv[kk].w * inv);
        }
    }

    // ---- x per-lane: load own 8 channels, facet-normalize via XOR1 ----
    f32x2 xh[4], ur[4];
    {
        const float* px = feat + (size_t)b * CC + c0;
        const float4 xa = *reinterpret_cast<const float4*>(px);
        const float4 xc = *reinterpret_cast<const float4*>(px + 4);
        xh[0] = f32x2{xa.x, xa.y}; xh[1] = f32x2{xa.z, xa.w};
        xh[2] = f32x2{xc.x, xc.y}; xh[3] = f32x2{xc.z, xc.w};
        f32x2 s2 = xh[0] * xh[0];
        s2 += xh[1] * xh[1];
        s2 += xh[2] * xh[2];
        s2 += xh[3] * xh[3];
        float s = s2.x + s2.y;
        s = dpp_add<DPP_XOR1>(s);          // partner lane: other facet half
        const float inv = rsq_guard(s);
        const f32x2 iv  = {inv, inv};
        const f32x2 ivl = {inv * LOG2E, inv * LOG2E};
#pragma unroll
        for (int j = 0; j < 4; ++j) { ur[j] = xh[j] * ivl; xh[j] *= iv; }
    }

    // ---- routing iterations: ONE barrier each ----
#pragma unroll
    for (int it = 0; it < 4; ++it) {
        const int p = it & 1;

        // fused logit -> softmax -> weighted-sum per owned k (R8 core)
        f32x2 pu[4] = {f32x2{0.f,0.f}, f32x2{0.f,0.f}, f32x2{0.f,0.f}, f32x2{0.f,0.f}};
#pragma unroll
        for (int kk = 0; kk < 4; ++kk) {
            const f32x2 z0 = unpack_bf16(zp[kk][0]);
            const f32x2 z1 = unpack_bf16(zp[kk][1]);
            const f32x2 z2 = unpack_bf16(zp[kk][2]);
            const f32x2 z3 = unpack_bf16(zp[kk][3]);
            f32x2 acc = z0 * ur[0];
            acc += z1 * ur[1];
            acc += z2 * ur[2];
            acc += z3 * ur[3];
            const float l = dpp_add<DPP_XOR1>(acc.x + acc.y);   // 16-d dot
            const float e = __builtin_amdgcn_exp2f(l);
            float su = dpp_add<DPP_XOR2>(e);                    // facet sum
            su = dpp_add<DPP_HMIR>(su);
            su = dpp_add<DPP_MIR>(su);
            const float wk = e * __builtin_amdgcn_rcpf(su);
            const f32x2 ws = {wk, wk};
            pu[0] += z0 * ws;
            pu[1] += z1 * ws;
            pu[2] += z2 * ws;
            pu[3] += z3 * ws;
        }
        // k-reduce over kgl (lane bits 4,5) via permlane swaps
#pragma unroll
        for (int j = 0; j < 4; ++j) {
            pu[j] = xor16_add2(pu[j]);
            pu[j] = xor32_add2(pu[j]);
        }
        if (kgl == 0) {
            float* dst = &part[p][wave][c0];
            *reinterpret_cast<float4*>(dst)     = make_float4(pu[0].x, pu[0].y, pu[1].x, pu[1].y);
            *reinterpret_cast<float4*>(dst + 4) = make_float4(pu[2].x, pu[2].y, pu[3].x, pu[3].y);
        }
        __syncthreads();

        // all-wave combine: lane sums rows 2*kgl, 2*kgl+1 for its channels,
        // then permlane16/32 completes the 8-row sum. No second barrier:
        // next write goes to buffer p^1.
        f32x2 un[4];
        {
            const float* r0 = &part[p][2 * kgl][c0];
            const float* r1 = &part[p][2 * kgl + 1][c0];
            const float4 a0 = *reinterpret_cast<const float4*>(r0);
            const float4 a1 = *reinterpret_cast<const float4*>(r0 + 4);
            const float4 b0 = *reinterpret_cast<const float4*>(r1);
            const float4 b1 = *reinterpret_cast<const float4*>(r1 + 4);
            un[0] = f32x2{a0.x + b0.x, a0.y + b0.y};
            un[1] = f32x2{a0.z + b0.z, a0.w + b0.w};
            un[2] = f32x2{a1.x + b1.x, a1.y + b1.y};
            un[3] = f32x2{a1.z + b1.z, a1.w + b1.w};
        }
#pragma unroll
        for (int j = 0; j < 4; ++j) {
            un[j] = xor16_add2(un[j]);
            un[j] = xor32_add2(un[j]);
            un[j] += xh[j];
        }

        if (it < 3) {
            f32x2 s2 = un[0] * un[0];
            s2 += un[1] * un[1];
            s2 += un[2] * un[2];
            s2 += un[3] * un[3];
            float s = s2.x + s2.y;
            s = dpp_add<DPP_XOR1>(s);
            const float ivl = rsq_guard(s) * LOG2E;
            const f32x2 iv = {ivl, ivl};
#pragma unroll
            for (int j = 0; j < 4; ++j) ur[j] = un[j] * iv;
        } else if (wave == 0 && kgl == 0) {
            float* dst = out + (size_t)b * CC + c0;
            *reinterpret_cast<float4*>(dst)     = make_float4(un[0].x, un[0].y, un[1].x, un[1].y);
            *reinterpret_cast<float4*>(dst + 4) = make_float4(un[2].x, un[2].y, un[3].x, un[3].y);
        }
    }
}

extern "C" void kernel_launch(void* const* d_in, const int* in_sizes, int n_in,
                              void* d_out, int out_size, void* d_ws, size_t ws_size,
                              hipStream_t stream) {
    const float* feat = (const float*)d_in[0];   // features [B,1,128] fp32
    const float* mp   = (const float*)d_in[1];   // metapath [B,1,128,128] fp32
    float* out = (float*)d_out;                  // [B,128] fp32
    const int B = in_sizes[0] / CC;              // 4096
    hete_routing_kernel<<<B, 512, 0, stream>>>(feat, mp, out);
}

// Round 15
// 48.039 us; speedup vs baseline: 1.7746x; 1.2842x over previous
//
#include <hip/hip_runtime.h>
#include <math.h>

// HeteAttention capsule routing, MI355X — bf16-packed register-resident z
// for 100% occupancy (VGPR <= 64 -> 8 waves/SIMD). BEST KERNEL (R8, 48.2us):
// restored verbatim after R9-R14 structural experiments all regressed.
// Effective BW 5.56 TB/s = 88% of the demonstrated 6.29 TB/s read ceiling;
// remaining gap is load/compute phase overlap, which six independent
// mechanisms (register/LDS prefetch, custom barriers, linear loads,
// barrier halving, 2-b interleave) failed to claim.
// B=4096, n=1, N=128, F=8 facets, D=16, n_iter=4, C=F*D=128.
// Grid 4096 blocks x 512 thr (8 waves); one b per block.
// Lane map (per wave): cg = lane&15 owns channels c = cg*8..cg*8+7; lane
// bit0 = half of facet f = cg>>1; kgl = lane>>4 (bits 4,5);
// kq = wave*4+kgl in [0,32) owns k = kq*4..kq*4+3.
// z slice: loaded fp32, L2-normalized per (k,facet) in fp32, then packed to
// bf16 pairs (v_cvt_pk_bf16_f32, RNE) -> 16 VGPRs. Unpack at use = shl16 /
// and-mask, reused for logit AND weighted sum within each kk step.
// Reductions: DPP quad_perm/mirrors (bit0 + softmax facet bits 1..3),
// permlane16/32 swaps (kgl). 8 wave-partials combined in LDS by threads
// 0..127. Softmax max-pass dropped (|logit|<=1, shift-invariant); exp2
// with log2e folded into broadcast u. absmax 0.0156 vs threshold 0.0597.

#define CC 128
#define LOG2E 1.44269504088896340736f

typedef float f32x2 __attribute__((ext_vector_type(2)));
typedef unsigned u32x2 __attribute__((ext_vector_type(2)));

template<int CTRL>
__device__ __forceinline__ float dpp_add(float x) {
    int y = __builtin_amdgcn_update_dpp(0, __float_as_int(x), CTRL, 0xF, 0xF, true);
    return x + __int_as_float(y);
}
#define DPP_XOR1 0xB1   // quad_perm [1,0,3,2]
#define DPP_XOR2 0x4E   // quad_perm [2,3,0,1]
#define DPP_HMIR 0x141  // row_half_mirror (^7; ==^4 when bits 0,1 uniform)
#define DPP_MIR  0x140  // row_mirror      (^15; ==^8 when bits 0..2 uniform)

__device__ __forceinline__ f32x2 xor16_add2(f32x2 v) {
    u32x2 r0 = __builtin_amdgcn_permlane16_swap(__float_as_uint(v.x), __float_as_uint(v.x), false, false);
    u32x2 r1 = __builtin_amdgcn_permlane16_swap(__float_as_uint(v.y), __float_as_uint(v.y), false, false);
    f32x2 o;
    o.x = __uint_as_float(r0.x) + __uint_as_float(r0.y);
    o.y = __uint_as_float(r1.x) + __uint_as_float(r1.y);
    return o;
}
__device__ __forceinline__ f32x2 xor32_add2(f32x2 v) {
    u32x2 r0 = __builtin_amdgcn_permlane32_swap(__float_as_uint(v.x), __float_as_uint(v.x), false, false);
    u32x2 r1 = __builtin_amdgcn_permlane32_swap(__float_as_uint(v.y), __float_as_uint(v.y), false, false);
    f32x2 o;
    o.x = __uint_as_float(r0.x) + __uint_as_float(r0.y);
    o.y = __uint_as_float(r1.x) + __uint_as_float(r1.y);
    return o;
}
__device__ __forceinline__ float rsq_guard(float s) {
    return __builtin_amdgcn_rsqf(fmaxf(s, 1e-24f));
}
__device__ __forceinline__ unsigned pack_bf16(float lo, float hi) {
    unsigned r;
    asm("v_cvt_pk_bf16_f32 %0, %1, %2" : "=v"(r) : "v"(lo), "v"(hi));
    return r;
}
__device__ __forceinline__ f32x2 unpack_bf16(unsigned u) {
    f32x2 r;
    r.x = __uint_as_float(u << 16);
    r.y = __uint_as_float(u & 0xFFFF0000u);
    return r;
}

__global__ __launch_bounds__(512, 8)
void hete_routing_kernel(const float* __restrict__ feat,   // [B, 128]
                         const float* __restrict__ mp,     // [B, 128, 128]
                         float* __restrict__ out)          // [B, 128]
{
    __shared__ float part[8][CC];   // 4 KB: per-wave partials
    __shared__ float u_s[CC];       // 512 B: broadcast u (pre-scaled log2e)

    const int t = threadIdx.x;
    const int wave = t >> 6;          // 0..7
    const int lane = t & 63;
    const int cg = lane & 15;
    const int kgl = lane >> 4;        // 0..3
    const int kq = wave * 4 + kgl;    // 0..31, owns k = kq*4 .. kq*4+3
    const int c0 = cg * 8;
    const int b = blockIdx.x;

    // ---- load z slice fp32 (8 dwordx4), normalize, pack to bf16 ----
    unsigned zp[4][4];                // 4 k's x 4 bf16-pairs (8 channels)
    {
        const float* zb = mp + (size_t)b * (128 * CC) + kq * 4 * CC + c0;
        float4 A[4], Bv[4];
#pragma unroll
        for (int kk = 0; kk < 4; ++kk) {
            A[kk]  = *reinterpret_cast<const float4*>(zb + kk * CC);
            Bv[kk] = *reinterpret_cast<const float4*>(zb + kk * CC + 4);
        }
#pragma unroll
        for (int kk = 0; kk < 4; ++kk) {
            float s = A[kk].x * A[kk].x + A[kk].y * A[kk].y
                    + A[kk].z * A[kk].z + A[kk].w * A[kk].w
                    + Bv[kk].x * Bv[kk].x + Bv[kk].y * Bv[kk].y
                    + Bv[kk].z * Bv[kk].z + Bv[kk].w * Bv[kk].w;
            s = dpp_add<DPP_XOR1>(s);
            const float inv = rsq_guard(s);
            zp[kk][0] = pack_bf16(A[kk].x * inv,  A[kk].y * inv);
            zp[kk][1] = pack_bf16(A[kk].z * inv,  A[kk].w * inv);
            zp[kk][2] = pack_bf16(Bv[kk].x * inv, Bv[kk].y * inv);
            zp[kk][3] = pack_bf16(Bv[kk].z * inv, Bv[kk].w * inv);
        }
    }

    // ---- combiner threads (t<128): x channel; x_hat via facet DPP reduce ----
    float xh = 0.f;
    if (t < CC) {
        const float xv = feat[(size_t)b * CC + t];
        float s = xv * xv;
        s = dpp_add<DPP_XOR1>(s);
        s = dpp_add<DPP_XOR2>(s);
        s = dpp_add<DPP_HMIR>(s);
        s = dpp_add<DPP_MIR>(s);
        xh = xv * rsq_guard(s);
        u_s[t] = xh * LOG2E;
    }
    __syncthreads();

    // ---- routing iterations ----
#pragma unroll
    for (int it = 0; it < 4; ++it) {
        // broadcast u (pre-scaled by log2e) from LDS
        f32x2 ur[4];
        {
            const float4 A  = *reinterpret_cast<const float4*>(&u_s[c0]);
            const float4 Bv = *reinterpret_cast<const float4*>(&u_s[c0 + 4]);
            ur[0] = f32x2{A.x, A.y};  ur[1] = f32x2{A.z, A.w};
            ur[2] = f32x2{Bv.x, Bv.y}; ur[3] = f32x2{Bv.z, Bv.w};
        }

        // fused logit -> softmax -> weighted-sum per owned k
        f32x2 pu[4] = {f32x2{0.f,0.f}, f32x2{0.f,0.f}, f32x2{0.f,0.f}, f32x2{0.f,0.f}};
#pragma unroll
        for (int kk = 0; kk < 4; ++kk) {
            const f32x2 z0 = unpack_bf16(zp[kk][0]);
            const f32x2 z1 = unpack_bf16(zp[kk][1]);
            const f32x2 z2 = unpack_bf16(zp[kk][2]);
            const f32x2 z3 = unpack_bf16(zp[kk][3]);
            f32x2 acc = z0 * ur[0];
            acc += z1 * ur[1];
            acc += z2 * ur[2];
            acc += z3 * ur[3];
            const float l = dpp_add<DPP_XOR1>(acc.x + acc.y);   // full 16-d dot
            const float e = __builtin_amdgcn_exp2f(l);
            float su = dpp_add<DPP_XOR2>(e);                    // facet sum
            su = dpp_add<DPP_HMIR>(su);
            su = dpp_add<DPP_MIR>(su);
            const float wk = e * __builtin_amdgcn_rcpf(su);
            const f32x2 ws = {wk, wk};
            pu[0] += z0 * ws;
            pu[1] += z1 * ws;
            pu[2] += z2 * ws;
            pu[3] += z3 * ws;
        }
        // reduce over kgl (lane bits 4,5) via permlane swaps (VALU)
#pragma unroll
        for (int j = 0; j < 4; ++j) {
            pu[j] = xor16_add2(pu[j]);
            pu[j] = xor32_add2(pu[j]);
        }
        if (kgl == 0) {
            float* dst = &part[wave][c0];
            *reinterpret_cast<float4*>(dst)     = make_float4(pu[0].x, pu[0].y, pu[1].x, pu[1].y);
            *reinterpret_cast<float4*>(dst + 4) = make_float4(pu[2].x, pu[2].y, pu[3].x, pu[3].y);
        }
        __syncthreads();

        // combiners: sum 8 wave-partials + x residual; norm or emit
        if (t < CC) {
            float un = xh;
#pragma unroll
            for (int j = 0; j < 8; ++j) un += part[j][t];
            if (it < 3) {
                float s = un * un;
                s = dpp_add<DPP_XOR1>(s);
                s = dpp_add<DPP_XOR2>(s);
                s = dpp_add<DPP_HMIR>(s);
                s = dpp_add<DPP_MIR>(s);
                u_s[t] = un * rsq_guard(s) * LOG2E;
            } else {
                out[(size_t)b * CC + t] = un;
            }
        }
        if (it < 3) __syncthreads();
    }
}

extern "C" void kernel_launch(void* const* d_in, const int* in_sizes, int n_in,
                              void* d_out, int out_size, void* d_ws, size_t ws_size,
                              hipStream_t stream) {
    const float* feat = (const float*)d_in[0];   // features [B,1,128] fp32
    const float* mp   = (const float*)d_in[1];   // metapath [B,1,128,128] fp32
    float* out = (float*)d_out;                  // [B,128] fp32
    const int B = in_sizes[0] / CC;              // 4096
    hete_routing_kernel<<<B, 512, 0, stream>>>(feat, mp, out);
}